// Round 1
// baseline (6389.384 us; speedup 1.0000x reference)
//
#include <hip/hip_runtime.h>
#include <cstdint>
#include <math.h>

#define N_TOK 32768
#define K_CODE 8192
#define DIM 512

#define DECAY_F 0.99f
#define OMD_F   0.01f

// output layout (flat float32, concatenated in return order)
#define OFF_LOSS 16777216            // N*D
#define OFF_PERP 16777217
#define OFF_EMB  16777218            // new_embedding [K*D]
#define OFF_CS   20971522            // new_cs [K]
#define OFF_EMAW 20979714            // new_ema_w [K*D]  (also used as dw accumulator)

// workspace layout (bytes)
// [0, 32768)      counts [K] f32      (memset 0)
// [32768, 32776)  loss_sum double     (memset 0)
// [32832, 65600)  enorm2 [K] f32
// [65600, ...)    indices [N] i32

#define TM 64
#define TK 64
#define BD 32
#define LDST 36   // LDS row stride (floats): 36*4=144 B, 144%16==0 -> float4-aligned; banks ok

__global__ void enorm_k(const float* __restrict__ emb, float* __restrict__ enorm2) {
    int k = blockIdx.x;
    int lane = threadIdx.x;  // 64
    const float4* row = (const float4*)(emb + (size_t)k * DIM);
    float4 a = row[lane];
    float4 b = row[lane + 64];
    float s = a.x*a.x + a.y*a.y + a.z*a.z + a.w*a.w
            + b.x*b.x + b.y*b.y + b.z*b.z + b.w*b.w;
    #pragma unroll
    for (int off = 32; off > 0; off >>= 1) s += __shfl_down(s, off);
    if (lane == 0) enorm2[k] = s;
}

// fused GEMM + row argmin: each block handles 64 tokens, loops over all K codes.
__global__ __launch_bounds__(256) void argmin_k(
        const float* __restrict__ x, const float* __restrict__ emb,
        const float* __restrict__ enorm2, int* __restrict__ out_idx) {
    __shared__ float sA[TM * LDST];
    __shared__ float sB[TK * LDST];

    const int tid = threadIdx.x;
    const int tg = tid >> 4;      // 0..15 (token group)
    const int cg = tid & 15;      // 0..15 (code group)
    const int rowBase = blockIdx.x * TM;

    float best[4] = {3.4e38f, 3.4e38f, 3.4e38f, 3.4e38f};
    int   bidx[4] = {0, 0, 0, 0};

    for (int kt = 0; kt < K_CODE; kt += TK) {
        float acc[4][4] = {};
        for (int d0 = 0; d0 < DIM; d0 += BD) {
            __syncthreads();
            // stage A (64x32) and B (64x32): 512 float4 each, 2 per thread
            #pragma unroll
            for (int p = 0; p < 2; ++p) {
                int l  = tid + p * 256;
                int r  = l >> 3;
                int c4 = (l & 7) << 2;
                float4 av = *(const float4*)(x   + (size_t)(rowBase + r) * DIM + d0 + c4);
                *(float4*)(sA + r * LDST + c4) = av;
                float4 bv = *(const float4*)(emb + (size_t)(kt + r) * DIM + d0 + c4);
                *(float4*)(sB + r * LDST + c4) = bv;
            }
            __syncthreads();
            #pragma unroll
            for (int d = 0; d < BD; d += 4) {
                float4 a[4], b[4];
                #pragma unroll
                for (int i = 0; i < 4; ++i)
                    a[i] = *(const float4*)(sA + (tg + 16*i) * LDST + d);
                #pragma unroll
                for (int j = 0; j < 4; ++j)
                    b[j] = *(const float4*)(sB + (cg + 16*j) * LDST + d);
                #pragma unroll
                for (int i = 0; i < 4; ++i)
                    #pragma unroll
                    for (int j = 0; j < 4; ++j)
                        acc[i][j] += a[i].x*b[j].x + a[i].y*b[j].y
                                   + a[i].z*b[j].z + a[i].w*b[j].w;
            }
        }
        // distances for this code tile; running argmin (first-index tie-break)
        #pragma unroll
        for (int j = 0; j < 4; ++j) {
            int col = kt + cg + 16*j;
            float e2 = enorm2[col];
            #pragma unroll
            for (int i = 0; i < 4; ++i) {
                float dist = e2 - 2.0f * acc[i][j];
                if (dist < best[i]) { best[i] = dist; bidx[i] = col; }
            }
        }
    }

    // cross-thread reduction: 16 candidates per token row
    __syncthreads();
    float* vals = sA;          // [64][16]
    int*   idxs = (int*)sB;    // [64][16]
    #pragma unroll
    for (int i = 0; i < 4; ++i) {
        vals[(tg + 16*i) * 16 + cg] = best[i];
        idxs[(tg + 16*i) * 16 + cg] = bidx[i];
    }
    __syncthreads();
    if (tid < TM) {
        float bv = vals[tid * 16];
        int   bi = idxs[tid * 16];
        #pragma unroll
        for (int c = 1; c < 16; ++c) {
            float v  = vals[tid * 16 + c];
            int   ix = idxs[tid * 16 + c];
            if (v < bv || (v == bv && ix < bi)) { bv = v; bi = ix; }
        }
        out_idx[rowBase + tid] = bi;
    }
}

// per-token: gather quantized row, scatter-add dw, counts, loss partial
__global__ void gather_k(const float* __restrict__ x, const float* __restrict__ emb,
                         const int* __restrict__ idx, float* __restrict__ q,
                         float* __restrict__ dw, float* __restrict__ counts,
                         double* __restrict__ loss_sum) {
    int n = blockIdx.x;
    int t = threadIdx.x;  // 128 threads, one float4 each
    int code = idx[n];

    float4 xv = *(const float4*)(x   + (size_t)n    * DIM + t * 4);
    float4 ev = *(const float4*)(emb + (size_t)code * DIM + t * 4);
    *(float4*)(q + (size_t)n * DIM + t * 4) = ev;

    float* dwp = dw + (size_t)code * DIM + t * 4;
    unsafeAtomicAdd(dwp + 0, xv.x);
    unsafeAtomicAdd(dwp + 1, xv.y);
    unsafeAtomicAdd(dwp + 2, xv.z);
    unsafeAtomicAdd(dwp + 3, xv.w);

    float dx = ev.x - xv.x, dy = ev.y - xv.y, dz = ev.z - xv.z, dwc = ev.w - xv.w;
    float s = dx*dx + dy*dy + dz*dz + dwc*dwc;
    #pragma unroll
    for (int off = 32; off > 0; off >>= 1) s += __shfl_down(s, off);
    __shared__ float wsum[2];
    if ((t & 63) == 0) wsum[t >> 6] = s;
    __syncthreads();
    if (t == 0) {
        atomicAdd(loss_sum, (double)(wsum[0] + wsum[1]));
        unsafeAtomicAdd(&counts[code], 1.0f);
    }
}

// single block: new_cs normalization, perplexity, loss scalar
__global__ void stats_k(const float* __restrict__ counts, const float* __restrict__ ema_cs,
                        const double* __restrict__ loss_sum, float* __restrict__ out) {
    __shared__ float sraw[K_CODE];
    __shared__ double rn[4], rp[4];
    __shared__ float s_scale;
    int t = threadIdx.x;  // 256
    double ntot = 0.0, pent = 0.0;
    for (int k = t; k < K_CODE; k += 256) {
        float c = counts[k];
        float raw = DECAY_F * ema_cs[k] + OMD_F * c;
        sraw[k] = raw;
        ntot += (double)raw;
        float p = c * (1.0f / N_TOK);
        pent += (double)(p * logf(p + 1e-10f));
    }
    #pragma unroll
    for (int off = 32; off > 0; off >>= 1) {
        ntot += __shfl_down(ntot, off);
        pent += __shfl_down(pent, off);
    }
    if ((t & 63) == 0) { rn[t >> 6] = ntot; rp[t >> 6] = pent; }
    __syncthreads();
    if (t == 0) {
        double nt = rn[0] + rn[1] + rn[2] + rn[3];
        double pe = rp[0] + rp[1] + rp[2] + rp[3];
        s_scale = (float)(nt / (nt + (double)K_CODE * 1e-5));
        out[OFF_LOSS] = (float)(0.25 * (*loss_sum) / ((double)N_TOK * (double)DIM));
        out[OFF_PERP] = (float)exp(-pe);
    }
    __syncthreads();
    float scale = s_scale;
    for (int k = t; k < K_CODE; k += 256)
        out[OFF_CS + k] = (sraw[k] + 1e-5f) * scale;
}

// elementwise: new_ema_w = .99*ema_w + .01*dw (in place over dw), new_embedding = new_ema_w / cs
__global__ void finalize_k(const float* __restrict__ ema_w, const float* __restrict__ new_cs,
                           float* __restrict__ emaw_out, float* __restrict__ emb_out) {
    size_t t = (size_t)blockIdx.x * 256 + threadIdx.x;
    float dwv = emaw_out[t];
    float nw = DECAY_F * ema_w[t] + OMD_F * dwv;
    emaw_out[t] = nw;
    emb_out[t] = nw / new_cs[t >> 9];
}

extern "C" void kernel_launch(void* const* d_in, const int* in_sizes, int n_in,
                              void* d_out, int out_size, void* d_ws, size_t ws_size,
                              hipStream_t stream) {
    const float* x      = (const float*)d_in[0];
    const float* emb    = (const float*)d_in[1];
    const float* ema_cs = (const float*)d_in[2];
    const float* ema_w  = (const float*)d_in[3];
    float* out = (float*)d_out;
    char*  ws  = (char*)d_ws;

    float*  counts   = (float*)ws;
    double* loss_sum = (double*)(ws + 32768);
    float*  enorm2   = (float*)(ws + 32832);
    int*    indices  = (int*)(ws + 65600);
    float*  dw       = out + OFF_EMAW;   // accumulate dw in the new_ema_w slot

    hipMemsetAsync(ws, 0, 32776, stream);                          // counts + loss_sum
    hipMemsetAsync(dw, 0, (size_t)K_CODE * DIM * sizeof(float), stream);

    enorm_k  <<<K_CODE, 64, 0, stream>>>(emb, enorm2);
    argmin_k <<<N_TOK / TM, 256, 0, stream>>>(x, emb, enorm2, indices);
    gather_k <<<N_TOK, 128, 0, stream>>>(x, emb, indices, out, dw, counts, loss_sum);
    stats_k  <<<1, 256, 0, stream>>>(counts, ema_cs, loss_sum, out);
    finalize_k<<<(K_CODE * DIM) / 256, 256, 0, stream>>>(ema_w, out + OFF_CS, dw, out + OFF_EMB);
}

// Round 2
// 1609.595 us; speedup vs baseline: 3.9696x; 3.9696x over previous
//
#include <hip/hip_runtime.h>
#include <cstdint>
#include <math.h>

#define N_TOK 32768
#define K_CODE 8192
#define DIM 512

#define DECAY_F 0.99f
#define OMD_F   0.01f

// output layout (flat float32, concatenated in return order)
#define OFF_LOSS 16777216            // N*D
#define OFF_PERP 16777217
#define OFF_EMB  16777218            // new_embedding [K*D]
#define OFF_CS   20971522            // new_cs [K]
#define OFF_EMAW 20979714            // new_ema_w [K*D]  (also used as dw accumulator)

// workspace layout (bytes)
// [0, 32768)        counts [K] f32      (memset 0)
// [32768, 32776)    loss_sum double     (memset 0)
// [32832, 65600)    enorm2 [K] f32
// [65600, 589888)   bestd [N*4] f32   (4 candidate slots per token: 2 K-halves x 2 col-halves)
// [589888, 1114176) besti [N*4] i32

typedef _Float16 f16;
typedef __attribute__((ext_vector_type(8))) _Float16 f16x8;
typedef __attribute__((ext_vector_type(4))) _Float16 f16x4;
typedef __attribute__((ext_vector_type(4))) float    f32x4;

// split fp32 -> (hi fp16, lo fp16); lo = RN16(x - (float)hi) ; x - hi is exact in fp32
__global__ void split_k(const float* __restrict__ src, f16* __restrict__ hp,
                        f16* __restrict__ lp) {
    size_t gid = (size_t)blockIdx.x * 256 + threadIdx.x;
    float4 v = ((const float4*)src)[gid];
    f16 h0 = (f16)v.x, h1 = (f16)v.y, h2 = (f16)v.z, h3 = (f16)v.w;
    f16 l0 = (f16)(v.x - (float)h0), l1 = (f16)(v.y - (float)h1);
    f16 l2 = (f16)(v.z - (float)h2), l3 = (f16)(v.w - (float)h3);
    *(f16x4*)(hp + gid * 4) = (f16x4){h0, h1, h2, h3};
    *(f16x4*)(lp + gid * 4) = (f16x4){l0, l1, l2, l3};
}

__global__ void enorm_k(const float* __restrict__ emb, float* __restrict__ enorm2) {
    int k = blockIdx.x;
    int lane = threadIdx.x;  // 64
    const float4* row = (const float4*)(emb + (size_t)k * DIM);
    float4 a = row[lane];
    float4 b = row[lane + 64];
    float s = a.x*a.x + a.y*a.y + a.z*a.z + a.w*a.w
            + b.x*b.x + b.y*b.y + b.z*b.z + b.w*b.w;
    #pragma unroll
    for (int off = 32; off > 0; off >>= 1) s += __shfl_down(s, off);
    if (lane == 0) enorm2[k] = s;
}

// MFMA fused GEMM+argmin. Block: 128 tokens x 128-code tiles, sweeping one K half.
// 4 waves in 2x2 grid; each wave: 4x4 of 16x16x32_f16 tiles, 3 products (hi*hi, hi*lo, lo*hi).
__global__ __launch_bounds__(256, 2) void argmin_mfma(
        const f16* __restrict__ xh, const f16* __restrict__ xl,
        const f16* __restrict__ eh, const f16* __restrict__ el,
        const float* __restrict__ enorm2,
        float* __restrict__ bestd, int* __restrict__ besti) {
    __shared__ f16 sA[2 * 128 * 32];   // [plane][row][k]  16 KB
    __shared__ f16 sB[2 * 128 * 32];

    const int tid  = threadIdx.x;
    const int lane = tid & 63;
    const int wave = tid >> 6;
    const int wr   = wave >> 1;      // token half of block tile
    const int wc   = wave & 1;       // code half of block tile
    const int m    = lane & 15;
    const int g4   = lane >> 4;

    const int rowBase = blockIdx.x * 128;
    const int kBase   = blockIdx.y * 4096;

    // staging assignment: wave 0->A hi, 1->A lo, 2->B hi, 3->B lo
    const int srow = lane >> 2;            // 0..15
    const int scol = (lane & 3) * 8;       // halfs (16 B)
    char* lbase = (char*)(wave < 2 ? sA : sB) + (wave & 1) * 8192;

    float best[16];
    int   bidx[16];
    #pragma unroll
    for (int i = 0; i < 16; ++i) { best[i] = 3.4e38f; bidx[i] = 0; }

    for (int kt = 0; kt < 4096; kt += 128) {
        f32x4 acc[4][4];
        #pragma unroll
        for (int a = 0; a < 4; ++a)
            #pragma unroll
            for (int b = 0; b < 4; ++b)
                acc[a][b] = (f32x4){0.f, 0.f, 0.f, 0.f};

        const f16* gA = (wave == 0 ? xh : xl) + (size_t)rowBase * DIM;
        const f16* gB = (wave == 2 ? eh : el) + (size_t)(kBase + kt) * DIM;
        const f16* gsrc = (wave < 2) ? gA : gB;

        for (int d0 = 0; d0 < DIM; d0 += 32) {
            __syncthreads();   // LDS safe to overwrite
            const f16* g = gsrc + d0 + (size_t)srow * DIM + scol;
            #pragma unroll
            for (int i = 0; i < 8; ++i) {
                __builtin_amdgcn_global_load_lds(
                    (const __attribute__((address_space(1))) unsigned int*)(g + (size_t)i * 16 * DIM),
                    (__attribute__((address_space(3))) unsigned int*)(lbase + i * 1024),
                    16, 0, 0);
            }
            __syncthreads();   // drains vmcnt before any frag read

            f16x8 ah[4], al[4], bh[4], bl[4];
            #pragma unroll
            for (int rt = 0; rt < 4; ++rt) {
                int off = (wr * 64 + rt * 16 + m) * 32 + g4 * 8;
                ah[rt] = *(const f16x8*)(sA + off);
                al[rt] = *(const f16x8*)(sA + 4096 + off);
            }
            #pragma unroll
            for (int ct = 0; ct < 4; ++ct) {
                int off = (wc * 64 + ct * 16 + m) * 32 + g4 * 8;
                bh[ct] = *(const f16x8*)(sB + off);
                bl[ct] = *(const f16x8*)(sB + 4096 + off);
            }
            #pragma unroll
            for (int rt = 0; rt < 4; ++rt)
                #pragma unroll
                for (int ct = 0; ct < 4; ++ct) {
                    acc[rt][ct] = __builtin_amdgcn_mfma_f32_16x16x32_f16(ah[rt], bl[ct], acc[rt][ct], 0, 0, 0);
                    acc[rt][ct] = __builtin_amdgcn_mfma_f32_16x16x32_f16(al[rt], bh[ct], acc[rt][ct], 0, 0, 0);
                    acc[rt][ct] = __builtin_amdgcn_mfma_f32_16x16x32_f16(ah[rt], bh[ct], acc[rt][ct], 0, 0, 0);
                }
        }

        // epilogue: dist = |e|^2 - 2 x.e ; running argmin (ascending col order, strict <)
        int colBase = kBase + kt + wc * 64;
        float e2[4];
        #pragma unroll
        for (int ct = 0; ct < 4; ++ct) e2[ct] = enorm2[colBase + ct * 16 + m];
        #pragma unroll
        for (int rt = 0; rt < 4; ++rt)
            #pragma unroll
            for (int reg = 0; reg < 4; ++reg) {
                float d = 3.4e38f; int c = 0;
                #pragma unroll
                for (int ct = 0; ct < 4; ++ct) {
                    float dist = e2[ct] - 2.0f * acc[rt][ct][reg];
                    if (dist < d) { d = dist; c = colBase + ct * 16 + m; }
                }
                int bi = rt * 4 + reg;
                if (d < best[bi]) { best[bi] = d; bidx[bi] = c; }
            }
    }

    // cross-lane reduce over the 16 col-classes (lanes differing in low 4 bits)
    #pragma unroll
    for (int rt = 0; rt < 4; ++rt)
        #pragma unroll
        for (int reg = 0; reg < 4; ++reg) {
            float d = best[rt * 4 + reg];
            int  ix = bidx[rt * 4 + reg];
            #pragma unroll
            for (int off = 1; off < 16; off <<= 1) {
                float od = __shfl_xor(d, off);
                int   oi = __shfl_xor(ix, off);
                if (od < d || (od == d && oi < ix)) { d = od; ix = oi; }
            }
            if (m == 0) {
                int tok = rowBase + wr * 64 + rt * 16 + g4 * 4 + reg;
                int slot = blockIdx.y * 2 + wc;   // 4 candidate slots per token
                bestd[tok * 4 + slot] = d;
                besti[tok * 4 + slot] = ix;
            }
        }
}

// per-token: combine 4 argmin candidates, gather quantized row, scatter dw/counts/loss
__global__ void gather_k(const float* __restrict__ x, const float* __restrict__ emb,
                         const float* __restrict__ bestd, const int* __restrict__ besti,
                         float* __restrict__ q, float* __restrict__ dw,
                         float* __restrict__ counts, double* __restrict__ loss_sum) {
    int n = blockIdx.x;
    int t = threadIdx.x;  // 128 threads, one float4 each

    float bd = bestd[n * 4];
    int   bc = besti[n * 4];
    #pragma unroll
    for (int j = 1; j < 4; ++j) {
        float d = bestd[n * 4 + j];
        int   c = besti[n * 4 + j];
        if (d < bd || (d == bd && c < bc)) { bd = d; bc = c; }
    }
    int code = bc;

    float4 xv = *(const float4*)(x   + (size_t)n    * DIM + t * 4);
    float4 ev = *(const float4*)(emb + (size_t)code * DIM + t * 4);
    *(float4*)(q + (size_t)n * DIM + t * 4) = ev;

    float* dwp = dw + (size_t)code * DIM + t * 4;
    unsafeAtomicAdd(dwp + 0, xv.x);
    unsafeAtomicAdd(dwp + 1, xv.y);
    unsafeAtomicAdd(dwp + 2, xv.z);
    unsafeAtomicAdd(dwp + 3, xv.w);

    float dx = ev.x - xv.x, dy = ev.y - xv.y, dz = ev.z - xv.z, dwc = ev.w - xv.w;
    float s = dx*dx + dy*dy + dz*dz + dwc*dwc;
    #pragma unroll
    for (int off = 32; off > 0; off >>= 1) s += __shfl_down(s, off);
    __shared__ float wsum[2];
    if ((t & 63) == 0) wsum[t >> 6] = s;
    __syncthreads();
    if (t == 0) {
        atomicAdd(loss_sum, (double)(wsum[0] + wsum[1]));
        unsafeAtomicAdd(&counts[code], 1.0f);
    }
}

// single block: new_cs normalization, perplexity, loss scalar
__global__ void stats_k(const float* __restrict__ counts, const float* __restrict__ ema_cs,
                        const double* __restrict__ loss_sum, float* __restrict__ out) {
    __shared__ float sraw[K_CODE];
    __shared__ double rn[4], rp[4];
    __shared__ float s_scale;
    int t = threadIdx.x;  // 256
    double ntot = 0.0, pent = 0.0;
    for (int k = t; k < K_CODE; k += 256) {
        float c = counts[k];
        float raw = DECAY_F * ema_cs[k] + OMD_F * c;
        sraw[k] = raw;
        ntot += (double)raw;
        float p = c * (1.0f / N_TOK);
        pent += (double)(p * logf(p + 1e-10f));
    }
    #pragma unroll
    for (int off = 32; off > 0; off >>= 1) {
        ntot += __shfl_down(ntot, off);
        pent += __shfl_down(pent, off);
    }
    if ((t & 63) == 0) { rn[t >> 6] = ntot; rp[t >> 6] = pent; }
    __syncthreads();
    if (t == 0) {
        double nt = rn[0] + rn[1] + rn[2] + rn[3];
        double pe = rp[0] + rp[1] + rp[2] + rp[3];
        s_scale = (float)(nt / (nt + (double)K_CODE * 1e-5));
        out[OFF_LOSS] = (float)(0.25 * (*loss_sum) / ((double)N_TOK * (double)DIM));
        out[OFF_PERP] = (float)exp(-pe);
    }
    __syncthreads();
    float scale = s_scale;
    for (int k = t; k < K_CODE; k += 256)
        out[OFF_CS + k] = (sraw[k] + 1e-5f) * scale;
}

// elementwise: new_ema_w = .99*ema_w + .01*dw (in place over dw), new_embedding = new_ema_w / cs
__global__ void finalize_k(const float* __restrict__ ema_w, const float* __restrict__ new_cs,
                           float* __restrict__ emaw_out, float* __restrict__ emb_out) {
    size_t t = (size_t)blockIdx.x * 256 + threadIdx.x;
    float dwv = emaw_out[t];
    float nw = DECAY_F * ema_w[t] + OMD_F * dwv;
    emaw_out[t] = nw;
    emb_out[t] = nw / new_cs[t >> 9];
}

extern "C" void kernel_launch(void* const* d_in, const int* in_sizes, int n_in,
                              void* d_out, int out_size, void* d_ws, size_t ws_size,
                              hipStream_t stream) {
    const float* x      = (const float*)d_in[0];
    const float* emb    = (const float*)d_in[1];
    const float* ema_cs = (const float*)d_in[2];
    const float* ema_w  = (const float*)d_in[3];
    float* out = (float*)d_out;
    char*  ws  = (char*)d_ws;

    float*  counts   = (float*)ws;
    double* loss_sum = (double*)(ws + 32768);
    float*  enorm2   = (float*)(ws + 32832);
    float*  bestd    = (float*)(ws + 65600);
    int*    besti    = (int*)(ws + 589888);
    float*  dw       = out + OFF_EMAW;   // accumulate dw in the new_ema_w slot

    // fp16 split planes in scratch regions of d_out (overwritten by later kernels):
    // x planes in out[0, N*D) floats; e planes in out[OFF_EMB, OFF_EMB+K*D) floats
    f16* xh = (f16*)out;
    f16* xl = xh + (size_t)N_TOK * DIM;
    f16* eh = (f16*)(out + OFF_EMB);
    f16* el = eh + (size_t)K_CODE * DIM;

    hipMemsetAsync(ws, 0, 32776, stream);                          // counts + loss_sum
    hipMemsetAsync(dw, 0, (size_t)K_CODE * DIM * sizeof(float), stream);

    split_k <<<(N_TOK * DIM) / 1024, 256, 0, stream>>>(x, xh, xl);
    split_k <<<(K_CODE * DIM) / 1024, 256, 0, stream>>>(emb, eh, el);
    enorm_k <<<K_CODE, 64, 0, stream>>>(emb, enorm2);
    argmin_mfma<<<dim3(N_TOK / 128, 2), 256, 0, stream>>>(xh, xl, eh, el, enorm2, bestd, besti);
    gather_k<<<N_TOK, 128, 0, stream>>>(x, emb, bestd, besti, out, dw, counts, loss_sum);
    stats_k <<<1, 256, 0, stream>>>(counts, ema_cs, loss_sum, out);
    finalize_k<<<(K_CODE * DIM) / 256, 256, 0, stream>>>(ema_w, out + OFF_CS, dw, out + OFF_EMB);
}

// Round 3
// 1353.343 us; speedup vs baseline: 4.7212x; 1.1893x over previous
//
#include <hip/hip_runtime.h>
#include <cstdint>
#include <math.h>

#define N_TOK 32768
#define K_CODE 8192
#define DIM 512

#define DECAY_F 0.99f
#define OMD_F   0.01f

// output layout (flat float32, concatenated in return order)
#define OFF_LOSS 16777216            // N*D
#define OFF_PERP 16777217
#define OFF_EMB  16777218            // new_embedding [K*D]
#define OFF_CS   20971522            // new_cs [K]
#define OFF_EMAW 20979714            // new_ema_w [K*D]

// workspace layout (bytes)
// [0, 32768)        counts_int [K] i32   (memset 0)
// [32768, 65536)    cursors [K] i32      (memset 0)
// [65536, 65544)    loss_sum double      (memset 0)
// [65600, 98368)    enorm2 [K] f32
// [98368, 229440)   idx [N] i32
// [229440, 360512)  tokenlist [N] i32
// [360512, 393284)  rowstart [K+1] i32
// bestu u64[N*4] lives in d_out's new_ema_w slot (dead until dw_fin_k)

typedef _Float16 f16;
typedef __attribute__((ext_vector_type(8))) _Float16 f16x8;
typedef __attribute__((ext_vector_type(4))) _Float16 f16x4;
typedef __attribute__((ext_vector_type(4))) float    f32x4;

// split fp32 -> (hi fp16, lo fp16); lo = RN16(x - (float)hi); x - hi exact in fp32
__global__ void split_k(const float* __restrict__ src, f16* __restrict__ hp,
                        f16* __restrict__ lp) {
    size_t gid = (size_t)blockIdx.x * 256 + threadIdx.x;
    float4 v = ((const float4*)src)[gid];
    f16 h0 = (f16)v.x, h1 = (f16)v.y, h2 = (f16)v.z, h3 = (f16)v.w;
    f16 l0 = (f16)(v.x - (float)h0), l1 = (f16)(v.y - (float)h1);
    f16 l2 = (f16)(v.z - (float)h2), l3 = (f16)(v.w - (float)h3);
    *(f16x4*)(hp + gid * 4) = (f16x4){h0, h1, h2, h3};
    *(f16x4*)(lp + gid * 4) = (f16x4){l0, l1, l2, l3};
}

__global__ void enorm_k(const float* __restrict__ emb, float* __restrict__ enorm2) {
    int k = blockIdx.x;
    int lane = threadIdx.x;  // 64
    const float4* row = (const float4*)(emb + (size_t)k * DIM);
    float4 a = row[lane];
    float4 b = row[lane + 64];
    float s = a.x*a.x + a.y*a.y + a.z*a.z + a.w*a.w
            + b.x*b.x + b.y*b.y + b.z*b.z + b.w*b.w;
    #pragma unroll
    for (int off = 32; off > 0; off >>= 1) s += __shfl_down(s, off);
    if (lane == 0) enorm2[k] = s;
}

// MFMA fused GEMM+argmin. Block: 128 tokens x 128-code tiles, sweeping K/4 codes.
// LDS tiles XOR-swizzled: physical colblock = logical ^ ((row>>1)&3)  (colblock = 16 B)
__global__ __launch_bounds__(256, 2) void argmin_mfma(
        const f16* __restrict__ xh, const f16* __restrict__ xl,
        const f16* __restrict__ eh, const f16* __restrict__ el,
        const float* __restrict__ enorm2,
        unsigned long long* __restrict__ bestu) {
    __shared__ f16 sA[2 * 128 * 32];   // [plane][row][k] 16 KB
    __shared__ f16 sB[2 * 128 * 32];

    const int tid  = threadIdx.x;
    const int lane = tid & 63;
    const int wave = tid >> 6;
    const int wr   = wave >> 1;
    const int wc   = wave & 1;
    const int m    = lane & 15;
    const int g4   = lane >> 4;
    const int cbp  = g4 ^ ((m >> 1) & 3);      // swizzled colblock for frag reads

    const int rowBase = blockIdx.x * 128;
    const int kBase   = blockIdx.y * (K_CODE / 4);

    // staging: wave 0->A hi, 1->A lo, 2->B hi, 3->B lo; lane l writes LDS at l*16B
    const int srow  = lane >> 2;
    const int scolh = (((lane & 3) ^ ((lane >> 3) & 3)) << 3);  // swizzled source col (halfs)
    char* lbase = (char*)(wave < 2 ? sA : sB) + (wave & 1) * 8192;

    float best[16];
    int   bidx[16];
    #pragma unroll
    for (int i = 0; i < 16; ++i) { best[i] = 3.4e38f; bidx[i] = 0; }

    for (int kt = 0; kt < K_CODE / 4; kt += 128) {
        f32x4 acc[4][4];
        #pragma unroll
        for (int a = 0; a < 4; ++a)
            #pragma unroll
            for (int b = 0; b < 4; ++b)
                acc[a][b] = (f32x4){0.f, 0.f, 0.f, 0.f};

        const f16* gA = (wave == 0 ? xh : xl) + (size_t)rowBase * DIM;
        const f16* gB = (wave == 2 ? eh : el) + (size_t)(kBase + kt) * DIM;
        const f16* gsrc = (wave < 2) ? gA : gB;

        for (int d0 = 0; d0 < DIM; d0 += 32) {
            __syncthreads();
            const f16* g = gsrc + d0 + (size_t)srow * DIM + scolh;
            #pragma unroll
            for (int i = 0; i < 8; ++i) {
                __builtin_amdgcn_global_load_lds(
                    (const __attribute__((address_space(1))) unsigned int*)(g + (size_t)i * 16 * DIM),
                    (__attribute__((address_space(3))) unsigned int*)(lbase + i * 1024),
                    16, 0, 0);
            }
            __syncthreads();

            f16x8 ah[4], al[4], bh[4], bl[4];
            #pragma unroll
            for (int rt = 0; rt < 4; ++rt) {
                int off = (wr * 64 + rt * 16 + m) * 32 + cbp * 8;
                ah[rt] = *(const f16x8*)(sA + off);
                al[rt] = *(const f16x8*)(sA + 4096 + off);
            }
            #pragma unroll
            for (int ct = 0; ct < 4; ++ct) {
                int off = (wc * 64 + ct * 16 + m) * 32 + cbp * 8;
                bh[ct] = *(const f16x8*)(sB + off);
                bl[ct] = *(const f16x8*)(sB + 4096 + off);
            }
            #pragma unroll
            for (int rt = 0; rt < 4; ++rt)
                #pragma unroll
                for (int ct = 0; ct < 4; ++ct) {
                    acc[rt][ct] = __builtin_amdgcn_mfma_f32_16x16x32_f16(ah[rt], bl[ct], acc[rt][ct], 0, 0, 0);
                    acc[rt][ct] = __builtin_amdgcn_mfma_f32_16x16x32_f16(al[rt], bh[ct], acc[rt][ct], 0, 0, 0);
                    acc[rt][ct] = __builtin_amdgcn_mfma_f32_16x16x32_f16(ah[rt], bh[ct], acc[rt][ct], 0, 0, 0);
                }
        }

        // dist = |e|^2 - 2 x.e ; running argmin (ascending col order, strict <)
        int colBase = kBase + kt + wc * 64;
        float e2[4];
        #pragma unroll
        for (int ct = 0; ct < 4; ++ct) e2[ct] = enorm2[colBase + ct * 16 + m];
        #pragma unroll
        for (int rt = 0; rt < 4; ++rt)
            #pragma unroll
            for (int reg = 0; reg < 4; ++reg) {
                float d = 3.4e38f; int c = 0;
                #pragma unroll
                for (int ct = 0; ct < 4; ++ct) {
                    float dist = e2[ct] - 2.0f * acc[rt][ct][reg];
                    if (dist < d) { d = dist; c = colBase + ct * 16 + m; }
                }
                int bi = rt * 4 + reg;
                if (d < best[bi]) { best[bi] = d; bidx[bi] = c; }
            }
    }

    __syncthreads();   // all waves done with sA/sB; reuse as combine scratch
    float* cd = (float*)sA;                 // [128]
    int*   ci = (int*)((char*)sA + 512);    // [128]

    #pragma unroll
    for (int rt = 0; rt < 4; ++rt)
        #pragma unroll
        for (int reg = 0; reg < 4; ++reg) {
            float d = best[rt * 4 + reg];
            int  ix = bidx[rt * 4 + reg];
            #pragma unroll
            for (int off = 1; off < 16; off <<= 1) {
                float od = __shfl_xor(d, off);
                int   oi = __shfl_xor(ix, off);
                if (od < d || (od == d && oi < ix)) { d = od; ix = oi; }
            }
            best[rt * 4 + reg] = d;
            bidx[rt * 4 + reg] = ix;
            if (wc == 1 && m == 0) {
                int tl = rt * 16 + g4 * 4 + reg;
                cd[wr * 64 + tl] = d;
                ci[wr * 64 + tl] = ix;
            }
        }
    __syncthreads();
    if (wc == 0 && m == 0) {
        #pragma unroll
        for (int rt = 0; rt < 4; ++rt)
            #pragma unroll
            for (int reg = 0; reg < 4; ++reg) {
                int tl = rt * 16 + g4 * 4 + reg;
                float d = best[rt * 4 + reg];
                int  ix = bidx[rt * 4 + reg];
                float od = cd[wr * 64 + tl];
                int   oi = ci[wr * 64 + tl];
                if (od < d || (od == d && oi < ix)) { d = od; ix = oi; }
                unsigned int fs = __float_as_uint(d);
                unsigned int key = fs ^ ((fs & 0x80000000u) ? 0xFFFFFFFFu : 0x80000000u);
                unsigned long long u = ((unsigned long long)key << 32) | (unsigned int)ix;
                bestu[(size_t)(rowBase + wr * 64 + tl) * 4 + blockIdx.y] = u;
            }
    }
}

// per token: min over 4 slots -> idx, count histogram
__global__ void bucket1_k(const unsigned long long* __restrict__ bestu,
                          int* __restrict__ idx, int* __restrict__ counts) {
    int n = blockIdx.x * 256 + threadIdx.x;
    const unsigned long long* p = bestu + (size_t)n * 4;
    unsigned long long u = p[0];
    if (p[1] < u) u = p[1];
    if (p[2] < u) u = p[2];
    if (p[3] < u) u = p[3];
    int code = (int)(u & 0xFFFFFFFFull);
    idx[n] = code;
    atomicAdd(&counts[code], 1);
}

// exclusive prefix sum over counts (single block)
__global__ void prefix_k(const int* __restrict__ counts, int* __restrict__ rowstart) {
    __shared__ int part[256];
    __shared__ int partsc[257];
    int t = threadIdx.x;
    int base = t * 32;
    int c[32];
    int s = 0;
    #pragma unroll
    for (int j = 0; j < 32; ++j) { c[j] = counts[base + j]; s += c[j]; }
    part[t] = s;
    __syncthreads();
    if (t == 0) {
        int r = 0;
        for (int i = 0; i < 256; ++i) { partsc[i] = r; r += part[i]; }
        partsc[256] = r;
    }
    __syncthreads();
    int off = partsc[t];
    #pragma unroll
    for (int j = 0; j < 32; ++j) { rowstart[base + j] = off; off += c[j]; }
    if (t == 255) rowstart[K_CODE] = partsc[256];
}

// scatter tokens into CSR lists
__global__ void scatter_k(const int* __restrict__ idx, const int* __restrict__ rowstart,
                          int* __restrict__ cursors, int* __restrict__ tokenlist) {
    int n = blockIdx.x * 256 + threadIdx.x;
    int code = idx[n];
    int pos = atomicAdd(&cursors[code], 1);
    tokenlist[rowstart[code] + pos] = n;
}

// gather q = emb[idx] and exact commitment-loss sum
__global__ void gather_q(const float* __restrict__ x, const float* __restrict__ emb,
                         const int* __restrict__ idx, float* __restrict__ q,
                         double* __restrict__ loss_sum) {
    float ls = 0.f;
    #pragma unroll
    for (int it = 0; it < 8; ++it) {
        size_t g = (size_t)blockIdx.x * 256 + threadIdx.x + (size_t)it * 524288;
        int n = (int)(g >> 7);
        int c = (int)(g & 127);
        float4 ev = ((const float4*)emb)[(size_t)idx[n] * 128 + c];
        float4 xv = ((const float4*)x)[g];
        ((float4*)q)[g] = ev;
        float dx = ev.x - xv.x, dy = ev.y - xv.y, dz = ev.z - xv.z, dw = ev.w - xv.w;
        ls += dx*dx + dy*dy + dz*dz + dw*dw;
    }
    #pragma unroll
    for (int off = 32; off > 0; off >>= 1) ls += __shfl_down(ls, off);
    __shared__ float wsum[4];
    int t = threadIdx.x;
    if ((t & 63) == 0) wsum[t >> 6] = ls;
    __syncthreads();
    if (t == 0) atomicAdd(loss_sum, (double)(wsum[0] + wsum[1] + wsum[2] + wsum[3]));
}

// single block: new_cs normalization, perplexity, loss scalar
__global__ void stats_k(const int* __restrict__ counts, const float* __restrict__ ema_cs,
                        const double* __restrict__ loss_sum, float* __restrict__ out) {
    __shared__ float sraw[K_CODE];
    __shared__ double rn[4], rp[4];
    __shared__ float s_scale;
    int t = threadIdx.x;  // 256
    double ntot = 0.0, pent = 0.0;
    for (int k = t; k < K_CODE; k += 256) {
        float c = (float)counts[k];
        float raw = DECAY_F * ema_cs[k] + OMD_F * c;
        sraw[k] = raw;
        ntot += (double)raw;
        float p = c * (1.0f / N_TOK);
        pent += (double)(p * logf(p + 1e-10f));
    }
    #pragma unroll
    for (int off = 32; off > 0; off >>= 1) {
        ntot += __shfl_down(ntot, off);
        pent += __shfl_down(pent, off);
    }
    if ((t & 63) == 0) { rn[t >> 6] = ntot; rp[t >> 6] = pent; }
    __syncthreads();
    if (t == 0) {
        double nt = rn[0] + rn[1] + rn[2] + rn[3];
        double pe = rp[0] + rp[1] + rp[2] + rp[3];
        s_scale = (float)(nt / (nt + (double)K_CODE * 1e-5));
        out[OFF_LOSS] = (float)(0.25 * (*loss_sum) / ((double)N_TOK * (double)DIM));
        out[OFF_PERP] = (float)exp(-pe);
    }
    __syncthreads();
    float scale = s_scale;
    for (int k = t; k < K_CODE; k += 256)
        out[OFF_CS + k] = (sraw[k] + 1e-5f) * scale;
}

// per code: dw = sum of assigned x rows; fused EMA + divide epilogue
__global__ __launch_bounds__(128) void dw_fin_k(
        const float* __restrict__ x, const float* __restrict__ ema_w,
        const int* __restrict__ rowstart, const int* __restrict__ tokenlist,
        const float* __restrict__ new_cs,
        float* __restrict__ emaw_out, float* __restrict__ emb_out) {
    int k = blockIdx.x;
    int t = threadIdx.x;  // 128, one float4 each
    int s = rowstart[k], e = rowstart[k + 1];
    float4 acc = {0.f, 0.f, 0.f, 0.f};
    for (int i = s; i < e; ++i) {
        int tok = tokenlist[i];
        float4 v = ((const float4*)(x + (size_t)tok * DIM))[t];
        acc.x += v.x; acc.y += v.y; acc.z += v.z; acc.w += v.w;
    }
    float4 w = ((const float4*)(ema_w + (size_t)k * DIM))[t];
    float cs = new_cs[k];
    float4 nw = {DECAY_F * w.x + OMD_F * acc.x, DECAY_F * w.y + OMD_F * acc.y,
                 DECAY_F * w.z + OMD_F * acc.z, DECAY_F * w.w + OMD_F * acc.w};
    ((float4*)(emaw_out + (size_t)k * DIM))[t] = nw;
    float4 eo = {nw.x / cs, nw.y / cs, nw.z / cs, nw.w / cs};
    ((float4*)(emb_out + (size_t)k * DIM))[t] = eo;
}

extern "C" void kernel_launch(void* const* d_in, const int* in_sizes, int n_in,
                              void* d_out, int out_size, void* d_ws, size_t ws_size,
                              hipStream_t stream) {
    const float* x      = (const float*)d_in[0];
    const float* emb    = (const float*)d_in[1];
    const float* ema_cs = (const float*)d_in[2];
    const float* ema_w  = (const float*)d_in[3];
    float* out = (float*)d_out;
    char*  ws  = (char*)d_ws;

    int*    counts   = (int*)ws;
    int*    cursors  = (int*)(ws + 32768);
    double* loss_sum = (double*)(ws + 65536);
    float*  enorm2   = (float*)(ws + 65600);
    int*    idx      = (int*)(ws + 98368);
    int*    tokenlist= (int*)(ws + 229440);
    int*    rowstart = (int*)(ws + 360512);

    // scratch in d_out regions that are dead until later kernels:
    f16* xh = (f16*)out;                       // [0, N*D) floats
    f16* xl = xh + (size_t)N_TOK * DIM;
    f16* eh = (f16*)(out + OFF_EMB);           // new_embedding slot
    f16* el = eh + (size_t)K_CODE * DIM;
    unsigned long long* bestu = (unsigned long long*)(out + OFF_EMAW);  // new_ema_w slot

    hipMemsetAsync(ws, 0, 65544, stream);   // counts + cursors + loss_sum

    split_k <<<(N_TOK * DIM) / 1024, 256, 0, stream>>>(x, xh, xl);
    split_k <<<(K_CODE * DIM) / 1024, 256, 0, stream>>>(emb, eh, el);
    enorm_k <<<K_CODE, 64, 0, stream>>>(emb, enorm2);
    argmin_mfma<<<dim3(N_TOK / 128, 4), 256, 0, stream>>>(xh, xl, eh, el, enorm2, bestu);
    bucket1_k<<<N_TOK / 256, 256, 0, stream>>>(bestu, idx, counts);
    prefix_k <<<1, 256, 0, stream>>>(counts, rowstart);
    scatter_k<<<N_TOK / 256, 256, 0, stream>>>(idx, rowstart, cursors, tokenlist);
    gather_q <<<2048, 256, 0, stream>>>(x, emb, idx, out, loss_sum);
    stats_k  <<<1, 256, 0, stream>>>(counts, ema_cs, loss_sum, out);
    dw_fin_k <<<K_CODE, 128, 0, stream>>>(x, ema_w, rowstart, tokenlist,
                                          out + OFF_CS, out + OFF_EMAW, out + OFF_EMB);
}